// Round 6
// baseline (103.612 us; speedup 1.0000x reference)
//
#include <hip/hip_runtime.h>

using short8 = __attribute__((ext_vector_type(8))) short;
using f32x4  = __attribute__((ext_vector_type(4))) float;

constexpr int D       = 64;
constexpr int K       = 1024;
constexpr int NROWS   = 32768;
constexpr int THREADS = 256;           // 4 waves: (2 row-groups) x (2 code-halves)
constexpr int RPB     = 64;            // rows per block
constexpr int NBLK    = NROWS / RPB;   // 512
constexpr int CHUNK   = 128;           // codes per chunk per half
constexpr int STEPS   = 512 / CHUNK;   // 4

__device__ __forceinline__ unsigned short f2bf(float f) {
    unsigned u = __builtin_bit_cast(unsigned, f);
    u = (u + 0x7FFFu + ((u >> 16) & 1u)) >> 16;   // RNE
    return (unsigned short)u;
}

__device__ __forceinline__ short8 pack8(float4 v0, float4 v1) {
    short8 pk;
    pk[0] = (short)f2bf(v0.x); pk[1] = (short)f2bf(v0.y);
    pk[2] = (short)f2bf(v0.z); pk[3] = (short)f2bf(v0.w);
    pk[4] = (short)f2bf(v1.x); pk[5] = (short)f2bf(v1.y);
    pk[6] = (short)f2bf(v1.z); pk[7] = (short)f2bf(v1.w);
    return pk;
}

// truncating bf16x2 pack: 1 v_perm per 2 values
__device__ __forceinline__ unsigned pk2(float f0, float f1) {
    return __builtin_amdgcn_perm(__builtin_bit_cast(unsigned, f1),
                                 __builtin_bit_cast(unsigned, f0), 0x07060302u);
}

__global__ __launch_bounds__(THREADS, 2) void vq_main(
    const float* __restrict__ x, const float* __restrict__ cb,
    float* __restrict__ qst, double* __restrict__ mse_acc,
    int* __restrict__ counts, int* __restrict__ done,
    float* __restrict__ out_loss, float* __restrict__ out_ppl) {

    __shared__ char  s_cb[2][2][CHUNK * 128];  // [half][dbuf], bf16 XOR-swizzled (64 KB)
    __shared__ int   s_hist[K];                // 4 KB
    __shared__ float s_sc[RPB][2];
    __shared__ int   s_sk[RPB][2];
    __shared__ int   s_kwin[RPB];
    __shared__ float s_red[4];
    __shared__ int   s_flag;

    const int tid  = threadIdx.x;
    const int lane = tid & 63;
    const int w    = __builtin_amdgcn_readfirstlane(tid >> 6);  // 0..3
    const int h    = w >> 1;          // code half: [h*512, h*512+512)
    const int rg2  = w & 1;           // 32-row group
    const int mrow = lane & 15;
    const int kgrp = lane >> 4;
    const int bbase = blockIdx.x * RPB;
    const int wbase = bbase + rg2 * 32;

    for (int i = tid; i < K; i += THREADS) s_hist[i] = 0;

    // resident B-frags: rows wbase+mrow and wbase+16+mrow (RNE, 16 VGPRs)
    short8 b00, b01, b10, b11;
    {
        const float* p0 = x + (size_t)(wbase + mrow) * D + kgrp * 8;
        b00 = pack8(*(const float4*)(p0),      *(const float4*)(p0 + 4));
        b01 = pack8(*(const float4*)(p0 + 32), *(const float4*)(p0 + 36));
        const float* p1 = p0 + (size_t)16 * D;
        b10 = pack8(*(const float4*)(p1),      *(const float4*)(p1 + 4));
        b11 = pack8(*(const float4*)(p1 + 32), *(const float4*)(p1 + 36));
    }

    // staging geometry: 256 threads stage 2 halves x CHUNK codes per step
    const int g  = tid & 7;           // dim-group of 8
    const int c0 = tid >> 3;          // 0..31
    const unsigned swz = (unsigned)((c0 & 7) << 4);

    // prologue: chunk 0 of both halves -> buf 0
#pragma unroll
    for (int i = 0; i < 4; ++i) {
#pragma unroll
        for (int hh = 0; hh < 2; ++hh) {
            const int code = c0 + 32 * i;
            const float* p = cb + (size_t)(hh * 512 + code) * D + g * 8;
            float4 va = *(const float4*)(p);
            float4 vb = *(const float4*)(p + 4);
            uint4 pk = { pk2(va.x, va.y), pk2(va.z, va.w), pk2(vb.x, vb.y), pk2(vb.z, vb.w) };
            *(uint4*)(&s_cb[hh][0][(unsigned)(code * 128 + g * 16) ^ swz]) = pk;
        }
    }
    __syncthreads();

    float bs0[4], bs1[4]; int bk0[4], bk1[4];
#pragma unroll
    for (int r = 0; r < 4; ++r) { bs0[r] = -3.4e38f; bk0[r] = 0; bs1[r] = -3.4e38f; bk1[r] = 0; }

    const unsigned aswz = (unsigned)((mrow & 7) << 4);

#pragma unroll
    for (int s = 0; s < STEPS; ++s) {
        // T14: issue next chunk's global loads before compute
        float4 va[8], vb[8];
        if (s + 1 < STEPS) {
#pragma unroll
            for (int i = 0; i < 4; ++i) {
#pragma unroll
                for (int hh = 0; hh < 2; ++hh) {
                    const float* p = cb + (size_t)(hh * 512 + (s + 1) * CHUNK + c0 + 32 * i) * D + g * 8;
                    va[i * 2 + hh] = *(const float4*)(p);
                    vb[i * 2 + hh] = *(const float4*)(p + 4);
                }
            }
        }

        // compute chunk s of this wave's half; one A-read feeds 2 row-group chains
        const char* base = s_cb[h][s & 1];
        const int kb0 = h * 512 + s * CHUNK;
#pragma unroll
        for (int t = 0; t < CHUNK / 16; ++t) {
            const int code = t * 16 + mrow;
            unsigned ab = ((unsigned)(code * 128 + kgrp * 16)) ^ aswz;
            short8 a0 = *(const short8*)(base + ab);
            short8 a1 = *(const short8*)(base + (ab ^ 64u));
            f32x4 z = {0.f, 0.f, 0.f, 0.f};
            f32x4 acc0 = __builtin_amdgcn_mfma_f32_16x16x32_bf16(a0, b00, z, 0, 0, 0);
            acc0       = __builtin_amdgcn_mfma_f32_16x16x32_bf16(a1, b01, acc0, 0, 0, 0);
            f32x4 acc1 = __builtin_amdgcn_mfma_f32_16x16x32_bf16(a0, b10, z, 0, 0, 0);
            acc1       = __builtin_amdgcn_mfma_f32_16x16x32_bf16(a1, b11, acc1, 0, 0, 0);
            const int kb = kb0 + t * 16 + kgrp * 4;
#pragma unroll
            for (int r = 0; r < 4; ++r) {       // k ascending per chain: '>' keeps smallest k
                if (acc0[r] > bs0[r]) { bs0[r] = acc0[r]; bk0[r] = kb + r; }
                if (acc1[r] > bs1[r]) { bs1[r] = acc1[r]; bk1[r] = kb + r; }
            }
        }

        // pack + write next chunk into the other buffer
        if (s + 1 < STEPS) {
#pragma unroll
            for (int i = 0; i < 4; ++i) {
#pragma unroll
                for (int hh = 0; hh < 2; ++hh) {
                    const int code = c0 + 32 * i;
                    const int idx = i * 2 + hh;
                    uint4 pk = { pk2(va[idx].x, va[idx].y), pk2(va[idx].z, va[idx].w),
                                 pk2(vb[idx].x, vb[idx].y), pk2(vb[idx].z, vb[idx].w) };
                    *(uint4*)(&s_cb[hh][(s + 1) & 1][(unsigned)(code * 128 + g * 16) ^ swz]) = pk;
                }
            }
        }
        __syncthreads();
    }

    // merge 4 chains per row-group (exact, smallest-k tie-break)
    float f0 = bs0[0]; int k0 = bk0[0];
    float f1 = bs1[0]; int k1 = bk1[0];
#pragma unroll
    for (int r = 1; r < 4; ++r) {
        if (bs0[r] > f0 || (bs0[r] == f0 && bk0[r] < k0)) { f0 = bs0[r]; k0 = bk0[r]; }
        if (bs1[r] > f1 || (bs1[r] == f1 && bk1[r] < k1)) { f1 = bs1[r]; k1 = bk1[r]; }
    }
    // combine the 4 kgrp copies
#pragma unroll
    for (int off = 16; off <= 32; off <<= 1) {
        float o0 = __shfl_xor(f0, off); int q0 = __shfl_xor(k0, off);
        float o1 = __shfl_xor(f1, off); int q1 = __shfl_xor(k1, off);
        if (o0 > f0 || (o0 == f0 && q0 < k0)) { f0 = o0; k0 = q0; }
        if (o1 > f1 || (o1 == f1 && q1 < k1)) { f1 = o1; k1 = q1; }
    }
    if (lane < 16) {
        s_sc[rg2 * 32 + lane][h] = f0;      s_sk[rg2 * 32 + lane][h] = k0;
        s_sc[rg2 * 32 + 16 + lane][h] = f1; s_sk[rg2 * 32 + 16 + lane][h] = k1;
    }
    __syncthreads();

    // cross-half merge (h=0 codes < h=1 codes, so tie -> h=0 automatically)
    if (tid < RPB) {
        float sA = s_sc[tid][0]; int kA = s_sk[tid][0];
        float sB = s_sc[tid][1]; int kB = s_sk[tid][1];
        int kwin = (sB > sA) ? kB : kA;
        s_kwin[tid] = kwin;
        atomicAdd(&s_hist[kwin], 1);
    }
    __syncthreads();

    // epilogue: 4 threads per row x 16 dims
    float mse = 0.f;
    {
        const int r  = tid >> 2;               // 0..63
        const int d0 = (tid & 3) * 16;
        const int k  = s_kwin[r];
        const int grow = bbase + r;
        const float* xr = x   + (size_t)grow * D + d0;
        const float* er = cb  + (size_t)k    * D + d0;
        float*       qr = qst + (size_t)grow * D + d0;
#pragma unroll
        for (int i = 0; i < 4; ++i) {
            float4 xv = reinterpret_cast<const float4*>(xr)[i];
            float4 ev = reinterpret_cast<const float4*>(er)[i];
            float dx = ev.x - xv.x, dy = ev.y - xv.y, dz = ev.z - xv.z, dw = ev.w - xv.w;
            float4 q = make_float4(xv.x + dx, xv.y + dy, xv.z + dz, xv.w + dw);
            reinterpret_cast<float4*>(qr)[i] = q;
            mse = fmaf(dx, dx, mse); mse = fmaf(dy, dy, mse);
            mse = fmaf(dz, dz, mse); mse = fmaf(dw, dw, mse);
        }
    }

    // flush histogram to global
    for (int i = tid; i < K; i += THREADS) {
        int v = s_hist[i];
        if (v) atomicAdd(&counts[i], v);
    }

    // block mse reduce
#pragma unroll
    for (int off = 32; off; off >>= 1) mse += __shfl_xor(mse, off);
    if (lane == 0) s_red[w] = mse;
    __threadfence();                    // release our hist/qst writes
    __syncthreads();
    if (tid == 0) {
        float m = s_red[0] + s_red[1] + s_red[2] + s_red[3];
        atomicAdd(mse_acc, (double)m);
        __threadfence();
        int old = atomicAdd(done, 1);
        s_flag = (old == NBLK - 1);
    }
    __syncthreads();

    // last block computes loss + perplexity
    if (s_flag) {
        __threadfence();                // acquire
        float term = 0.f;
        for (int i = tid; i < K; i += THREADS) {
            float p = (float)atomicAdd(&counts[i], 0) * (1.0f / (float)NROWS);
            term += p * logf(p + 1e-10f);
        }
#pragma unroll
        for (int off = 32; off; off >>= 1) term += __shfl_xor(term, off);
        if (lane == 0) s_red[w] = term;
        __syncthreads();
        if (tid == 0) {
            float ssum = s_red[0] + s_red[1] + s_red[2] + s_red[3];
            double mt = atomicAdd(mse_acc, 0.0);
            *out_ppl  = expf(-ssum);
            *out_loss = (float)(1.25 * mt * (1.0 / ((double)NROWS * D)));
        }
    }
}

extern "C" void kernel_launch(void* const* d_in, const int* in_sizes, int n_in,
                              void* d_out, int out_size, void* d_ws, size_t ws_size,
                              hipStream_t stream) {
    const float* x  = (const float*)d_in[0];   // (32768, 64)
    const float* cb = (const float*)d_in[1];   // (1024, 64)
    float* out = (float*)d_out;                // [qst | loss | ppl]

    char* ws = (char*)d_ws;
    int*    counts = (int*)   (ws);            // 4096 B
    double* mse    = (double*)(ws + 4096);     // 8 B
    int*    done   = (int*)   (ws + 4104);     // 4 B

    hipMemsetAsync(ws, 0, 4108, stream);

    vq_main<<<NBLK, THREADS, 0, stream>>>(x, cb, out, mse, counts, done,
                                          out + (size_t)out_size - 2,
                                          out + (size_t)out_size - 1);
}

// Round 7
// 33.899 us; speedup vs baseline: 3.0565x; 3.0565x over previous
//
#include <hip/hip_runtime.h>

using short8 = __attribute__((ext_vector_type(8))) short;
using f32x4  = __attribute__((ext_vector_type(4))) float;

constexpr int D       = 64;
constexpr int K       = 1024;
constexpr int NROWS   = 32768;
constexpr int THREADS = 512;           // 8 waves: 4 row-groups x 2 code-halves
constexpr int RPB     = 128;           // rows per block
constexpr int NBLK    = NROWS / RPB;   // 256 = one block per CU

__device__ __forceinline__ unsigned short f2bf(float f) {
    unsigned u = __builtin_bit_cast(unsigned, f);
    u = (u + 0x7FFFu + ((u >> 16) & 1u)) >> 16;   // RNE
    return (unsigned short)u;
}

__device__ __forceinline__ short8 pack8(float4 v0, float4 v1) {
    short8 pk;
    pk[0] = (short)f2bf(v0.x); pk[1] = (short)f2bf(v0.y);
    pk[2] = (short)f2bf(v0.z); pk[3] = (short)f2bf(v0.w);
    pk[4] = (short)f2bf(v1.x); pk[5] = (short)f2bf(v1.y);
    pk[6] = (short)f2bf(v1.z); pk[7] = (short)f2bf(v1.w);
    return pk;
}

// truncating bf16x2 pack: 1 v_perm per 2 values (codebook only)
__device__ __forceinline__ unsigned pk2(float f0, float f1) {
    return __builtin_amdgcn_perm(__builtin_bit_cast(unsigned, f1),
                                 __builtin_bit_cast(unsigned, f0), 0x07060302u);
}

__global__ __launch_bounds__(THREADS, 2) void vq_main(
    const float* __restrict__ x, const float* __restrict__ cb,
    float* __restrict__ qst, double* __restrict__ mse_acc, int* __restrict__ counts) {

    __shared__ unsigned short s_cb[K * D];     // 128 KB bf16, XOR-swizzled, whole codebook
    __shared__ int   s_hist[K];                // 4 KB
    __shared__ float s_sc[RPB][2];
    __shared__ int   s_sk[RPB][2];
    __shared__ int   s_kwin[RPB];
    __shared__ float s_red[8];

    const int tid  = threadIdx.x;
    const int lane = tid & 63;
    const int w    = __builtin_amdgcn_readfirstlane(tid >> 6);  // 0..7
    const int h    = w & 1;           // code half: [h*512, +512)
    const int rg   = w >> 1;          // row-group 0..3 (32 rows each)
    const int mrow = lane & 15;
    const int kgrp = lane >> 4;
    const int bbase = blockIdx.x * RPB;
    const int wbase = bbase + rg * 32;

    for (int i = tid; i < K; i += THREADS) s_hist[i] = 0;

    // resident B-frags: rows wbase+mrow and wbase+16+mrow (RNE, 16 VGPRs)
    short8 b00, b01, b10, b11;
    {
        const float* p0 = x + (size_t)(wbase + mrow) * D + kgrp * 8;
        b00 = pack8(*(const float4*)(p0),      *(const float4*)(p0 + 4));
        b01 = pack8(*(const float4*)(p0 + 32), *(const float4*)(p0 + 36));
        const float* p1 = p0 + (size_t)16 * D;
        b10 = pack8(*(const float4*)(p1),      *(const float4*)(p1 + 4));
        b11 = pack8(*(const float4*)(p1 + 32), *(const float4*)(p1 + 36));
    }

    // stage entire codebook once: g = dim-group, codes c0 + 64*i
    {
        const int g  = tid & 7;
        const int c0 = tid >> 3;          // 0..63
#pragma unroll
        for (int i = 0; i < 16; ++i) {
            const int code = c0 + 64 * i;
            const float* p = cb + (size_t)code * D + g * 8;
            float4 va = *(const float4*)(p);
            float4 vb = *(const float4*)(p + 4);
            uint4 pk = { pk2(va.x, va.y), pk2(va.z, va.w), pk2(vb.x, vb.y), pk2(vb.z, vb.w) };
            unsigned byte = ((unsigned)(code * 128 + g * 16)) ^ (unsigned)((code & 7) << 4);
            *(uint4*)((char*)s_cb + byte) = pk;
        }
    }
    __syncthreads();

    // scan this wave's half: 32 subtiles, one A-read feeds 2 row-group chains
    float bs0[4], bs1[4]; int bk0[4], bk1[4];
#pragma unroll
    for (int r = 0; r < 4; ++r) { bs0[r] = -3.4e38f; bk0[r] = 0; bs1[r] = -3.4e38f; bk1[r] = 0; }

    const char* base = (const char*)s_cb + h * 512 * 128;   // this half's bytes
    const unsigned aswz = (unsigned)((mrow & 7) << 4);

#pragma unroll
    for (int t = 0; t < 32; ++t) {
        const int ci = t * 16 + mrow;                        // code within half
        unsigned ab = ((unsigned)(ci * 128 + kgrp * 16)) ^ aswz;
        short8 a0 = *(const short8*)(base + ab);
        short8 a1 = *(const short8*)(base + (ab ^ 64u));
        f32x4 z = {0.f, 0.f, 0.f, 0.f};
        f32x4 acc0 = __builtin_amdgcn_mfma_f32_16x16x32_bf16(a0, b00, z, 0, 0, 0);
        acc0       = __builtin_amdgcn_mfma_f32_16x16x32_bf16(a1, b01, acc0, 0, 0, 0);
        f32x4 acc1 = __builtin_amdgcn_mfma_f32_16x16x32_bf16(a0, b10, z, 0, 0, 0);
        acc1       = __builtin_amdgcn_mfma_f32_16x16x32_bf16(a1, b11, acc1, 0, 0, 0);
        const int kb = h * 512 + t * 16 + kgrp * 4;
#pragma unroll
        for (int r = 0; r < 4; ++r) {        // k ascending per chain: '>' keeps smallest k
            if (acc0[r] > bs0[r]) { bs0[r] = acc0[r]; bk0[r] = kb + r; }
            if (acc1[r] > bs1[r]) { bs1[r] = acc1[r]; bk1[r] = kb + r; }
        }
    }

    // merge 4 chains per row-group (exact, smallest-k tie-break)
    float f0 = bs0[0]; int k0 = bk0[0];
    float f1 = bs1[0]; int k1 = bk1[0];
#pragma unroll
    for (int r = 1; r < 4; ++r) {
        if (bs0[r] > f0 || (bs0[r] == f0 && bk0[r] < k0)) { f0 = bs0[r]; k0 = bk0[r]; }
        if (bs1[r] > f1 || (bs1[r] == f1 && bk1[r] < k1)) { f1 = bs1[r]; k1 = bk1[r]; }
    }
    // combine the 4 kgrp copies of each x-row
#pragma unroll
    for (int off = 16; off <= 32; off <<= 1) {
        float o0 = __shfl_xor(f0, off); int q0 = __shfl_xor(k0, off);
        float o1 = __shfl_xor(f1, off); int q1 = __shfl_xor(k1, off);
        if (o0 > f0 || (o0 == f0 && q0 < k0)) { f0 = o0; k0 = q0; }
        if (o1 > f1 || (o1 == f1 && q1 < k1)) { f1 = o1; k1 = q1; }
    }
    if (lane < 16) {
        s_sc[rg * 32 + lane][h]      = f0;  s_sk[rg * 32 + lane][h]      = k0;
        s_sc[rg * 32 + 16 + lane][h] = f1;  s_sk[rg * 32 + 16 + lane][h] = k1;
    }
    __syncthreads();

    // cross-half merge (h=0 codes < h=1 codes: tie -> h=0 keeps smaller k)
    if (tid < RPB) {
        float sA = s_sc[tid][0]; int kA = s_sk[tid][0];
        float sB = s_sc[tid][1]; int kB = s_sk[tid][1];
        int kwin = (sB > sA) ? kB : kA;
        s_kwin[tid] = kwin;
        atomicAdd(&s_hist[kwin], 1);
    }
    __syncthreads();

    // epilogue: 4 threads per row x 16 dims (coalesced)
    float mse = 0.f;
    {
        const int r  = tid >> 2;               // 0..127
        const int d0 = (tid & 3) * 16;
        const int k  = s_kwin[r];
        const int grow = bbase + r;
        const float* xr = x   + (size_t)grow * D + d0;
        const float* er = cb  + (size_t)k    * D + d0;
        float*       qr = qst + (size_t)grow * D + d0;
#pragma unroll
        for (int i = 0; i < 4; ++i) {
            float4 xv = reinterpret_cast<const float4*>(xr)[i];
            float4 ev = reinterpret_cast<const float4*>(er)[i];
            float dx = ev.x - xv.x, dy = ev.y - xv.y, dz = ev.z - xv.z, dw = ev.w - xv.w;
            float4 q = make_float4(xv.x + dx, xv.y + dy, xv.z + dz, xv.w + dw);
            reinterpret_cast<float4*>(qr)[i] = q;
            mse = fmaf(dx, dx, mse); mse = fmaf(dy, dy, mse);
            mse = fmaf(dz, dz, mse); mse = fmaf(dw, dw, mse);
        }
    }

    // flush histogram to global
    for (int i = tid; i < K; i += THREADS) {
        int v = s_hist[i];
        if (v) atomicAdd(&counts[i], v);
    }

    // block mse reduce -> one double atomic
#pragma unroll
    for (int off = 32; off; off >>= 1) mse += __shfl_xor(mse, off);
    if (lane == 0) s_red[w] = mse;
    __syncthreads();
    if (tid == 0) {
        float m = 0.f;
#pragma unroll
        for (int i = 0; i < 8; ++i) m += s_red[i];
        atomicAdd(mse_acc, (double)m);
    }
}

// ---- finalize: loss + perplexity (kernel boundary = coherence point) ----
__global__ void vq_final(const int* __restrict__ counts,
                         const double* __restrict__ mse_acc,
                         float* __restrict__ out_loss,
                         float* __restrict__ out_ppl) {
    __shared__ float wsum[16];
    const int t = threadIdx.x;  // 1024 threads
    float p = (float)counts[t] * (1.0f / (float)NROWS);
    float term = p * logf(p + 1e-10f);
#pragma unroll
    for (int off = 32; off; off >>= 1) term += __shfl_xor(term, off);
    if ((t & 63) == 0) wsum[t >> 6] = term;
    __syncthreads();
    if (t == 0) {
        float s = 0.f;
#pragma unroll
        for (int i = 0; i < 16; ++i) s += wsum[i];
        *out_ppl  = expf(-s);
        *out_loss = (float)(1.25 * (*mse_acc) * (1.0 / ((double)NROWS * D)));
    }
}

extern "C" void kernel_launch(void* const* d_in, const int* in_sizes, int n_in,
                              void* d_out, int out_size, void* d_ws, size_t ws_size,
                              hipStream_t stream) {
    const float* x  = (const float*)d_in[0];   // (32768, 64)
    const float* cb = (const float*)d_in[1];   // (1024, 64)
    float* out = (float*)d_out;                // [qst | loss | ppl]

    char* ws = (char*)d_ws;
    int*    counts = (int*)   (ws);            // 4096 B
    double* mse    = (double*)(ws + 4096);     // 8 B

    hipMemsetAsync(ws, 0, 4104, stream);

    vq_main <<<NBLK, THREADS, 0, stream>>>(x, cb, out, mse, counts);
    vq_final<<<1, 1024, 0, stream>>>(counts, mse,
                                     out + (size_t)out_size - 2,
                                     out + (size_t)out_size - 1);
}